// Round 5
// baseline (380.287 us; speedup 1.0000x reference)
//
#include <hip/hip_runtime.h>
#include <hip/hip_bf16.h>
#include <cstdint>

#define TT 2048
#define DD 1024
#define NH 16
#define HD 64
#define NB 4
#define SCALING 0.125f
#define LOG2E 1.44269504088896340736f
#define QSCALE (0.125f * 1.44269504088896340736f)   // SCALING * LOG2E folded into Q

typedef __bf16 bf16;
typedef __attribute__((ext_vector_type(8))) __bf16 bf16x8;
typedef __attribute__((ext_vector_type(4))) __bf16 bf16x4;
typedef __attribute__((ext_vector_type(4))) float f32x4;

__device__ __forceinline__ void gload_lds16(const bf16* g, bf16* l) {
    __builtin_amdgcn_global_load_lds(
        (__attribute__((address_space(1))) const void*)g,
        (__attribute__((address_space(3))) void*)l, 16, 0, 0);
}

// ---------------- prep: fused fp32->bf16 convert + weight transpose ----------------
__global__ __launch_bounds__(256) void k_prep(const float* __restrict__ x, bf16* __restrict__ xb,
                                              const float* __restrict__ Wq, const float* __restrict__ Wk,
                                              const float* __restrict__ Wv, const float* __restrict__ Wo,
                                              bf16* __restrict__ Wt) {
    __shared__ float tile_s[32][33];
    int bid = blockIdx.x, tid = threadIdx.x;
    if (bid < 8192) {
        size_t i = ((size_t)bid * 256 + tid) * 4;
        float4 v = *(const float4*)(x + i);
        bf16x4 o;
        o[0] = (bf16)v.x; o[1] = (bf16)v.y; o[2] = (bf16)v.z; o[3] = (bf16)v.w;
        *(bf16x4*)(xb + i) = o;
        return;
    }
    int b2 = bid - 8192;                 // [0,4096)
    int mat = b2 >> 10, tl = b2 & 1023;
    int n0 = (tl & 31) * 32, k0 = (tl >> 5) * 32;
    const float* w = mat == 0 ? Wq : (mat == 1 ? Wk : (mat == 2 ? Wv : Wo));
    int tx = tid & 31, ty = tid >> 5;    // ty 0..7
#pragma unroll
    for (int i = 0; i < 4; i++)
        tile_s[ty + 8 * i][tx] = w[(size_t)(k0 + ty + 8 * i) * DD + n0 + tx];
    __syncthreads();
#pragma unroll
    for (int i = 0; i < 4; i++)
        Wt[(size_t)mat * DD * DD + (size_t)(n0 + ty + 8 * i) * DD + k0 + tx] = (bf16)tile_s[tx][ty + 8 * i];
}

// ---------------- 128x128 bf16 GEMM mainloop, double-buffered staging ----------------
// Prefetch K-tile i+1 into the alternate LDS pair before computing tile i; the
// end-of-iter barrier (compiler vmcnt(0)+s_barrier) then drains a load with a full
// compute-phase of flight time. Alternate pair is safe: last read in iter i-1,
// which ended with a barrier.
__device__ __forceinline__ void gemm128_main(const bf16* __restrict__ A, const bf16* __restrict__ Bt,
                                             int m0, int n0, int K,
                                             bf16* smem, f32x4 acc[4][4]) {
    const int tid = threadIdx.x;
    const int w = tid >> 6, lane = tid & 63;
    const int wr = w >> 1, wc = w & 1, quad = lane >> 4, l16 = lane & 15;
    f32x4 zero = {0.f, 0.f, 0.f, 0.f};
#pragma unroll
    for (int mi = 0; mi < 4; mi++)
#pragma unroll
        for (int ni = 0; ni < 4; ni++) acc[mi][ni] = zero;

    // staging constants: 2 chunks for A, 2 for B per thread
    int cidx[2], arow[2], kc[2];
#pragma unroll
    for (int j = 0; j < 2; j++) {
        int idx = w * 128 + j * 64 + lane;          // 512 16B-chunks per tile
        cidx[j] = idx * 8;
        arow[j] = idx >> 2;
        kc[j] = (idx & 3) * 8;
    }
    const bf16* Ab = A + (size_t)m0 * K;
    const bf16* Bb = Bt + (size_t)n0 * K;

    // prefetch tile 0 into buffer 0
#pragma unroll
    for (int j = 0; j < 2; j++) {
        gload_lds16(Ab + (size_t)arow[j] * K + kc[j], smem + cidx[j]);
        gload_lds16(Bb + (size_t)arow[j] * K + kc[j], smem + 4096 + cidx[j]);
    }
    __syncthreads();

    const int NT = K >> 5;
    for (int kt = 0; kt < NT; kt++) {
        bf16* cur = smem + (kt & 1) * 8192;
        if (kt + 1 < NT) {
            bf16* nxt = smem + ((kt + 1) & 1) * 8192;
            int k0 = (kt + 1) * 32;
#pragma unroll
            for (int j = 0; j < 2; j++) {
                gload_lds16(Ab + (size_t)arow[j] * K + k0 + kc[j], nxt + cidx[j]);
                gload_lds16(Bb + (size_t)arow[j] * K + k0 + kc[j], nxt + 4096 + cidx[j]);
            }
        }
        bf16x8 af[4], bfv[4];
#pragma unroll
        for (int i = 0; i < 4; i++)
            af[i] = *(const bf16x8*)(cur + (wr * 64 + i * 16 + l16) * 32 + quad * 8);
#pragma unroll
        for (int i = 0; i < 4; i++)
            bfv[i] = *(const bf16x8*)(cur + 4096 + (wc * 64 + i * 16 + l16) * 32 + quad * 8);
#pragma unroll
        for (int mi = 0; mi < 4; mi++)
#pragma unroll
            for (int ni = 0; ni < 4; ni++)
                acc[mi][ni] = __builtin_amdgcn_mfma_f32_16x16x32_bf16(af[mi], bfv[ni], acc[mi][ni], 0, 0, 0);
        __syncthreads();               // drains prefetch(kt+1); guards buffer reuse
    }
}

// ---------------- GEMM 1 (fused with mask-flag reduction) ----------------
// V is written s-permuted per 64-block: pi(a*16+q*4+r) = q*16+a*4+r, so the attention
// kernel's PV B-fragment is one contiguous (swizzled) b128 read.
__global__ __launch_bounds__(256) void k_gemm_qkv(const bf16* __restrict__ Xb, const bf16* __restrict__ Wt,
                                                  const float* __restrict__ bq, const float* __restrict__ bk,
                                                  const float* __restrict__ bv,
                                                  bf16* __restrict__ qb, bf16* __restrict__ kb,
                                                  bf16* __restrict__ vt,
                                                  const float* __restrict__ mask, int* __restrict__ flags) {
    __shared__ bf16 smem[16384];         // 32 KB: dbuf GEMM staging; reused as 64x132 V-transpose
    __shared__ int s_any[4];
    const int bid = blockIdx.x, tid = threadIdx.x;
    const int grp = bid / 7, rem = bid % 7;

    if (rem >= 3) {
        // ---- mask-flag block ----
        int fid = grp * 4 + (rem - 3);               // [0,2048)
        int st = fid & 31, tt = (fid >> 5) & 15, bbm = fid >> 9;
        const float* mp = mask + ((size_t)bbm * TT + tt * 128) * TT + st * 64;
        int c = (tid & 15) * 4;
        int r0 = tid >> 4;
        int any = 0;
        for (int r = r0; r < 128; r += 16) {
            float4 v = *(const float4*)(mp + (size_t)r * TT + c);
            any |= (v.x != 0.f) | (v.y != 0.f) | (v.z != 0.f) | (v.w != 0.f);
        }
        any = __any(any) ? 1 : 0;
        if ((tid & 63) == 0) s_any[tid >> 6] = any;
        __syncthreads();
        if (tid == 0)
            flags[(bbm * 16 + tt) * 32 + st] = s_any[0] | s_any[1] | s_any[2] | s_any[3];
        return;
    }

    // ---- GEMM block ----
    int g = grp * 3 + rem;                           // [0,1536)
    int bx = g % 24, by = g / 24;
    int m0 = by * 128, n0 = bx * 128;
    f32x4 acc[4][4];
    gemm128_main(Xb, Wt, m0, n0, DD, smem, acc);

    const int w = tid >> 6, lane = tid & 63;
    const int wr = w >> 1, wc = w & 1, quad = lane >> 4, l16 = lane & 15;
    const int which = n0 >> 10;                      // 0=q,1=k,2=v (uniform per block)
    const int bbk = m0 >> 11, tbase = m0 & 2047;

    if (which < 2) {
        const float* bias = which == 0 ? bq : bk;
#pragma unroll
        for (int mi = 0; mi < 4; mi++)
#pragma unroll
            for (int ni = 0; ni < 4; ni++) {
                int nn = (n0 & 1023) + wc * 64 + ni * 16 + l16;
                int h = nn >> 6, d = nn & 63;
                float bb_ = bias[nn];
#pragma unroll
                for (int r = 0; r < 4; r++) {
                    int t = tbase + wr * 64 + mi * 16 + quad * 4 + r;
                    float v = acc[mi][ni][r] + bb_;
                    if (which == 0)
                        qb[(((size_t)bbk * NH + h) * TT + t) * HD + d] = (bf16)(v * QSCALE);
                    else
                        kb[(((size_t)bbk * NH + h) * TT + t) * HD + d] = (bf16)v;
                }
            }
    } else {
        // V: transpose through LDS -> coalesced 16B stores into vt [B,H,64,T], t pi-permuted
        const int nn0 = n0 & 1023;                   // 64-aligned
#pragma unroll
        for (int phase = 0; phase < 2; phase++) {
            __syncthreads();
            if (wc == phase) {
#pragma unroll
                for (int mi = 0; mi < 4; mi++)
#pragma unroll
                    for (int ni = 0; ni < 4; ni++) {
                        int nn_l = ni * 16 + l16;
                        float bb_ = bv[nn0 + phase * 64 + nn_l];
#pragma unroll
                        for (int r = 0; r < 4; r++)
                            // pi: t_l = wr*64 + mi*16 + quad*4 + r  ->  wr*64 + quad*16 + mi*4 + r
                            smem[nn_l * 132 + wr * 64 + quad * 16 + mi * 4 + r] = (bf16)(acc[mi][ni][r] + bb_);
                    }
            }
            __syncthreads();
            int hh = (nn0 + phase * 64) >> 6;
#pragma unroll
            for (int i = 0; i < 4; i++) {
                int idx = i * 256 + tid;             // 1024 16B-chunks (64 rows x 16)
                int rr = idx >> 4, cc = (idx & 15) * 8;
                bf16x8 vv = *(const bf16x8*)(smem + rr * 132 + cc);
                *(bf16x8*)(vt + (((size_t)bbk * NH + hh) * HD + rr) * TT + tbase + cc) = vv;
            }
        }
    }
}

// ---------------- flash attention v4: dbuf K/V staging, hoisted Q frags, b128 V ----------------
__global__ __launch_bounds__(256, 4) void k_attn(const bf16* __restrict__ qb, const bf16* __restrict__ kb,
                                                 const bf16* __restrict__ vt, const float* __restrict__ mask,
                                                 const int* __restrict__ flags, bf16* __restrict__ ob) {
    __shared__ bf16 SB[4][4096];   // 32 KB: buf0 = SB[0](K),SB[1](V); buf1 = SB[2](K),SB[3](V)
    __shared__ int s_anyflag;      // Q is staged through SB[2..3] then lives in registers

    const int tq0 = blockIdx.x * 128;
    const int h = blockIdx.y, bb = blockIdx.z;
    const int tid = threadIdx.x, w = tid >> 6, lane = tid & 63;
    const int quad = lane >> 4, l16 = lane & 15;

    const bf16* Qg = qb + (((size_t)bb * NH + h) * TT + tq0) * HD;
    const bf16* Kg = kb + ((size_t)bb * NH + h) * TT * HD;
    const bf16* Vg = vt + ((size_t)bb * NH + h) * HD * TT;

    // loop-invariant staging constants (2 chunks each for K and V per thread)
    int cidx[2], koff[2], voff[2];
#pragma unroll
    for (int j = 0; j < 2; j++) {
        int idx = (w * 2 + j) * 64 + lane;
        int row = idx >> 3, m = idx & 7;
        cidx[j] = idx * 8;
        koff[j] = row * HD + ((m ^ (row & 7)) * 8);
        voff[j] = row * TT + ((m ^ (row & 7)) * 8);
    }

    // stage Q into SB[2..3] (swizzled), prefetch K/V tile 0 into buf0
#pragma unroll
    for (int j = 0; j < 4; j++) {
        int idx = (w * 4 + j) * 64 + lane;
        int row = idx >> 3, m = idx & 7;
        gload_lds16(Qg + row * HD + (m ^ (row & 7)) * 8, &SB[2][0] + idx * 8);
    }
#pragma unroll
    for (int j = 0; j < 2; j++) {
        gload_lds16(Kg + koff[j], SB[0] + cidx[j]);
        gload_lds16(Vg + voff[j], SB[1] + cidx[j]);
    }

    const int fbase = (bb * 16 + blockIdx.x) * 32;
    {
        int f0 = (tid < 32) ? flags[fbase + tid] : 0;
        if (tid < 64) { int a = __any(f0 != 0) ? 1 : 0; if (tid == 0) s_anyflag = a; }
    }

    bf16x8 ones;
#pragma unroll
    for (int i = 0; i < 8; i++) ones[i] = (bf16)1.0f;

    f32x4 oa[2][4];
    f32x4 lacc[2];
    f32x4 zero = {0.f, 0.f, 0.f, 0.f};
#pragma unroll
    for (int qi = 0; qi < 2; qi++) {
        lacc[qi] = zero;
#pragma unroll
        for (int ni = 0; ni < 4; ni++) oa[qi][ni] = zero;
    }

    __syncthreads();                    // drains Q + tile0; publishes s_anyflag
    const int anyflag = s_anyflag;

    // hoist Q fragments (loop-invariant across s): aq[kd][qi]
    bf16x8 aq[2][2];
#pragma unroll
    for (int kd = 0; kd < 2; kd++) {
        const int csw = ((kd * 4 + quad) ^ (l16 & 7)) * 8;
#pragma unroll
        for (int qi = 0; qi < 2; qi++)
            aq[kd][qi] = *(const bf16x8*)(&SB[2][0] + (w * 32 + qi * 16 + l16) * 64 + csw);
    }

#define ATTN_COMPUTE(Ks, Vs, S0)                                                              \
    {                                                                                         \
        f32x4 st[4][2];                                                                       \
        _Pragma("unroll") for (int si = 0; si < 4; si++)                                      \
            _Pragma("unroll") for (int qi = 0; qi < 2; qi++) st[si][qi] = zero;               \
        _Pragma("unroll") for (int kd = 0; kd < 2; kd++) {                                    \
            const int csw = ((kd * 4 + quad) ^ (l16 & 7)) * 8;                                \
            bf16x8 kf[4];                                                                     \
            _Pragma("unroll") for (int si = 0; si < 4; si++)                                  \
                kf[si] = *(const bf16x8*)((Ks) + (si * 16 + l16) * 64 + csw);                 \
            _Pragma("unroll") for (int si = 0; si < 4; si++)                                  \
                _Pragma("unroll") for (int qi = 0; qi < 2; qi++)                              \
                    st[si][qi] = __builtin_amdgcn_mfma_f32_16x16x32_bf16(kf[si], aq[kd][qi],  \
                                                                        st[si][qi], 0, 0, 0);\
        }                                                                                     \
        if (anyflag && flags[fbase + ((S0) >> 6)]) {                                          \
            const float* mp = mask + ((size_t)bb * TT + tq0) * TT + (S0);                     \
            _Pragma("unroll") for (int si = 0; si < 4; si++)                                  \
                _Pragma("unroll") for (int qi = 0; qi < 2; qi++)                              \
                    _Pragma("unroll") for (int r = 0; r < 4; r++)                             \
                        st[si][qi][r] += mp[(size_t)(w * 32 + qi * 16 + l16) * TT             \
                                            + si * 16 + quad * 4 + r] * LOG2E;                \
        }                                                                                     \
        bf16 ep[4][2][4];                                                                     \
        _Pragma("unroll") for (int si = 0; si < 4; si++)                                      \
            _Pragma("unroll") for (int qi = 0; qi < 2; qi++)                                  \
                _Pragma("unroll") for (int r = 0; r < 4; r++)                                 \
                    ep[si][qi][r] = (bf16)exp2f(st[si][qi][r]);                               \
        _Pragma("unroll") for (int kk = 0; kk < 2; kk++) {                                    \
            bf16x8 ap[2];                                                                     \
            _Pragma("unroll") for (int qi = 0; qi < 2; qi++)                                  \
                _Pragma("unroll") for (int j = 0; j < 8; j++)                                 \
                    ap[qi][j] = ep[2 * kk + (j >> 2)][qi][j & 3];                             \
            bf16x8 bv8[4];                                                                    \
            _Pragma("unroll") for (int ni = 0; ni < 4; ni++)                                  \
                bv8[ni] = *(const bf16x8*)((Vs) + (ni * 16 + l16) * 64                        \
                                           + ((quad * 2 + kk) ^ (l16 & 7)) * 8);              \
            _Pragma("unroll") for (int qi = 0; qi < 2; qi++)                                  \
                lacc[qi] = __builtin_amdgcn_mfma_f32_16x16x32_bf16(ap[qi], ones, lacc[qi],    \
                                                                   0, 0, 0);                  \
            _Pragma("unroll") for (int qi = 0; qi < 2; qi++)                                  \
                _Pragma("unroll") for (int ni = 0; ni < 4; ni++)                              \
                    oa[qi][ni] = __builtin_amdgcn_mfma_f32_16x16x32_bf16(ap[qi], bv8[ni],     \
                                                                         oa[qi][ni], 0, 0, 0);\
        }                                                                                     \
    }

    // iter 0 (tile 0 in buf0); no prefetch in flight yet
    ATTN_COMPUTE(SB[0], SB[1], 0)
    __syncthreads();                    // everyone done with Q-frag reads + tile0
    // prefetch tile 1 into buf1 (overwrites the staged-Q region; frags are in regs)
#pragma unroll
    for (int j = 0; j < 2; j++) {
        gload_lds16(Kg + 64 * HD + koff[j], SB[2] + cidx[j]);
        gload_lds16(Vg + 64 + voff[j], SB[3] + cidx[j]);
    }
    __syncthreads();                    // drains tile1 (one exposed latency per block)

    for (int i = 1; i < 32; i++) {
        const int cur = i & 1, nxt = cur ^ 1;
        if (i < 31) {
            const int sn = (i + 1) * 64;
#pragma unroll
            for (int j = 0; j < 2; j++) {
                gload_lds16(Kg + sn * HD + koff[j], SB[2 * nxt] + cidx[j]);
                gload_lds16(Vg + sn + voff[j], SB[2 * nxt + 1] + cidx[j]);
            }
        }
        ATTN_COMPUTE(SB[2 * cur], SB[2 * cur + 1], i * 64)
        __syncthreads();                // drains prefetch(i+1); guards buffer reuse
    }
#undef ATTN_COMPUTE

    // epilogue: normalize by row sums, write O as [B,T,D] bf16
#pragma unroll
    for (int qi = 0; qi < 2; qi++)
#pragma unroll
        for (int r = 0; r < 4; r++) {
            float inv = 1.f / lacc[qi][r];
            int trow = tq0 + w * 32 + qi * 16 + quad * 4 + r;
#pragma unroll
            for (int ni = 0; ni < 4; ni++) {
                float v = oa[qi][ni][r] * inv;
                ob[((size_t)bb * TT + trow) * DD + h * HD + ni * 16 + l16] = (bf16)v;
            }
        }
}

// ---------------- GEMM 2: O @ Wo + bo -> fp32 out ----------------
__global__ __launch_bounds__(256) void k_gemm_out(const bf16* __restrict__ Ob, const bf16* __restrict__ Wot,
                                                  const float* __restrict__ bo, float* __restrict__ out) {
    __shared__ bf16 smem[16384];
    int m0 = blockIdx.y * 128, n0 = blockIdx.x * 128;
    f32x4 acc[4][4];
    gemm128_main(Ob, Wot, m0, n0, DD, smem, acc);

    const int tid = threadIdx.x, w = tid >> 6, lane = tid & 63;
    const int wr = w >> 1, wc = w & 1, quad = lane >> 4, l16 = lane & 15;
#pragma unroll
    for (int mi = 0; mi < 4; mi++)
#pragma unroll
        for (int ni = 0; ni < 4; ni++) {
            int gn = n0 + wc * 64 + ni * 16 + l16;
            float bb_ = bo[gn];
#pragma unroll
            for (int r = 0; r < 4; r++) {
                int gm = m0 + wr * 64 + mi * 16 + quad * 4 + r;
                out[(size_t)gm * DD + gn] = acc[mi][ni][r] + bb_;
            }
        }
}

// ---------------- launch ----------------
extern "C" void kernel_launch(void* const* d_in, const int* in_sizes, int n_in,
                              void* d_out, int out_size, void* d_ws, size_t ws_size,
                              hipStream_t stream) {
    const float* hidden = (const float*)d_in[0];
    const float* mask   = (const float*)d_in[1];
    const float* Wq     = (const float*)d_in[2];
    const float* bq     = (const float*)d_in[3];
    const float* Wk     = (const float*)d_in[4];
    const float* bk     = (const float*)d_in[5];
    const float* Wv     = (const float*)d_in[6];
    const float* bv     = (const float*)d_in[7];
    const float* Wo     = (const float*)d_in[8];
    const float* bo     = (const float*)d_in[9];
    float* out = (float*)d_out;
    char* ws = (char*)d_ws;

    const size_t MB = 1024 * 1024;
    bf16* Xb   = (bf16*)(ws);               // 16 MB  [8192][1024]
    bf16* Wt   = (bf16*)(ws + 16 * MB);     //  8 MB  [4][1024][1024] n-major
    bf16* qb   = (bf16*)(ws + 24 * MB);     // 16 MB  [B][H][T][64] (pre-scaled by SCALING*LOG2E)
    bf16* kb   = (bf16*)(ws + 40 * MB);     // 16 MB  [B][H][T][64]
    bf16* vt   = (bf16*)(ws + 56 * MB);     // 16 MB  [B][H][64][T], t pi-permuted per 64-block
    bf16* ob   = (bf16*)(ws + 72 * MB);     // 16 MB  [8192][1024]
    int* flags = (int*)(ws + 88 * MB);      //  8 KB  [4][16][32]

    hipLaunchKernelGGL(k_prep, dim3(12288), dim3(256), 0, stream, hidden, Xb, Wq, Wk, Wv, Wo, Wt);
    hipLaunchKernelGGL(k_gemm_qkv, dim3(3584), dim3(256), 0, stream, Xb, Wt, bq, bk, bv, qb, kb, vt, mask, flags);
    hipLaunchKernelGGL(k_attn, dim3(16, 16, 4), dim3(256), 0, stream, qb, kb, vt, mask, flags, ob);
    hipLaunchKernelGGL(k_gemm_out, dim3(8, 64), dim3(256), 0, stream, ob, Wt + (size_t)3 * DD * DD, bo, out);
}

// Round 6
// 360.717 us; speedup vs baseline: 1.0543x; 1.0543x over previous
//
#include <hip/hip_runtime.h>
#include <hip/hip_bf16.h>
#include <cstdint>

#define TT 2048
#define DD 1024
#define NH 16
#define HD 64
#define NB 4
#define SCALING 0.125f
#define LOG2E 1.44269504088896340736f
#define QSCALE (0.125f * 1.44269504088896340736f)   // SCALING * LOG2E folded into Q

typedef __bf16 bf16;
typedef __attribute__((ext_vector_type(8))) __bf16 bf16x8;
typedef __attribute__((ext_vector_type(4))) __bf16 bf16x4;
typedef __attribute__((ext_vector_type(4))) float f32x4;

__device__ __forceinline__ void gload_lds16(const bf16* g, bf16* l) {
    __builtin_amdgcn_global_load_lds(
        (__attribute__((address_space(1))) const void*)g,
        (__attribute__((address_space(3))) void*)l, 16, 0, 0);
}

// ---------------- prep: fused fp32->bf16 convert + weight transpose ----------------
__global__ __launch_bounds__(256) void k_prep(const float* __restrict__ x, bf16* __restrict__ xb,
                                              const float* __restrict__ Wq, const float* __restrict__ Wk,
                                              const float* __restrict__ Wv, const float* __restrict__ Wo,
                                              bf16* __restrict__ Wt) {
    __shared__ float tile_s[32][33];
    int bid = blockIdx.x, tid = threadIdx.x;
    if (bid < 8192) {
        size_t i = ((size_t)bid * 256 + tid) * 4;
        float4 v = *(const float4*)(x + i);
        bf16x4 o;
        o[0] = (bf16)v.x; o[1] = (bf16)v.y; o[2] = (bf16)v.z; o[3] = (bf16)v.w;
        *(bf16x4*)(xb + i) = o;
        return;
    }
    int b2 = bid - 8192;                 // [0,4096)
    int mat = b2 >> 10, tl = b2 & 1023;
    int n0 = (tl & 31) * 32, k0 = (tl >> 5) * 32;
    const float* w = mat == 0 ? Wq : (mat == 1 ? Wk : (mat == 2 ? Wv : Wo));
    int tx = tid & 31, ty = tid >> 5;    // ty 0..7
#pragma unroll
    for (int i = 0; i < 4; i++)
        tile_s[ty + 8 * i][tx] = w[(size_t)(k0 + ty + 8 * i) * DD + n0 + tx];
    __syncthreads();
#pragma unroll
    for (int i = 0; i < 4; i++)
        Wt[(size_t)mat * DD * DD + (size_t)(n0 + ty + 8 * i) * DD + k0 + tx] = (bf16)tile_s[tx][ty + 8 * i];
}

// ---------------- 128x128 bf16 GEMM mainloop: BK=64, single-buffer, XOR-swizzled LDS ----
// 32 MFMAs per barrier (vs 16 at BK=32) halves the vmcnt(0)+s_barrier drain frequency.
// LDS rows are 64 elem (128 B); 16B-chunk m within a row holds global chunk m^(row&7),
// so fragment reads (csw below) spread over all 32 banks -> no conflicts (R2-proven).
__device__ __forceinline__ void gemm128_main(const bf16* __restrict__ A, const bf16* __restrict__ Bt,
                                             int m0, int n0, int K,
                                             bf16* smem, f32x4 acc[4][4]) {
    const int tid = threadIdx.x;
    const int w = tid >> 6, lane = tid & 63;
    const int wr = w >> 1, wc = w & 1, quad = lane >> 4, l16 = lane & 15;
    f32x4 zero = {0.f, 0.f, 0.f, 0.f};
#pragma unroll
    for (int mi = 0; mi < 4; mi++)
#pragma unroll
        for (int ni = 0; ni < 4; ni++) acc[mi][ni] = zero;

    // staging constants: 1024 16B-chunks per 128x64 tile -> 4 per thread per matrix
    int cidx[4], goff[4];
#pragma unroll
    for (int j = 0; j < 4; j++) {
        int idx = (w * 4 + j) * 64 + lane;
        int row = idx >> 3, m = idx & 7;
        cidx[j] = idx * 8;
        goff[j] = row * K + (m ^ (row & 7)) * 8;   // swizzled source within the 128B row seg
    }
    const bf16* Ab = A + (size_t)m0 * K;
    const bf16* Bb = Bt + (size_t)n0 * K;

    for (int k0 = 0; k0 < K; k0 += 64) {
        if (k0) __syncthreads();
#pragma unroll
        for (int j = 0; j < 4; j++) {
            gload_lds16(Ab + k0 + goff[j], smem + cidx[j]);
            gload_lds16(Bb + k0 + goff[j], smem + 8192 + cidx[j]);
        }
        __syncthreads();
#pragma unroll
        for (int kd = 0; kd < 2; kd++) {
            const int csw = ((kd * 4 + quad) ^ (l16 & 7)) * 8;
            bf16x8 af[4], bfv[4];
#pragma unroll
            for (int i = 0; i < 4; i++)
                af[i] = *(const bf16x8*)(smem + (wr * 64 + i * 16 + l16) * 64 + csw);
#pragma unroll
            for (int i = 0; i < 4; i++)
                bfv[i] = *(const bf16x8*)(smem + 8192 + (wc * 64 + i * 16 + l16) * 64 + csw);
#pragma unroll
            for (int mi = 0; mi < 4; mi++)
#pragma unroll
                for (int ni = 0; ni < 4; ni++)
                    acc[mi][ni] = __builtin_amdgcn_mfma_f32_16x16x32_bf16(af[mi], bfv[ni], acc[mi][ni], 0, 0, 0);
        }
    }
}

// ---------------- GEMM 1 (fused with mask-flag reduction) ----------------
// V is written s-permuted per 64-block: pi(a*16+q*4+r) = q*16+a*4+r, so the attention
// kernel's PV B-fragment is one contiguous (swizzled) b128 read. Q/K epilogues go
// through an LDS transpose (stride 72) -> coalesced 16B stores.
__global__ __launch_bounds__(256) void k_gemm_qkv(const bf16* __restrict__ Xb, const bf16* __restrict__ Wt,
                                                  const float* __restrict__ bq, const float* __restrict__ bk,
                                                  const float* __restrict__ bv,
                                                  bf16* __restrict__ qb, bf16* __restrict__ kb,
                                                  bf16* __restrict__ vt,
                                                  const float* __restrict__ mask, int* __restrict__ flags) {
    __shared__ bf16 smem[16384];         // 32 KB: GEMM staging; reused for epilogue transposes
    __shared__ int s_any[4];
    const int bid = blockIdx.x, tid = threadIdx.x;
    const int grp = bid / 7, rem = bid % 7;

    if (rem >= 3) {
        // ---- mask-flag block ----
        int fid = grp * 4 + (rem - 3);               // [0,2048)
        int st = fid & 31, tt = (fid >> 5) & 15, bbm = fid >> 9;
        const float* mp = mask + ((size_t)bbm * TT + tt * 128) * TT + st * 64;
        int c = (tid & 15) * 4;
        int r0 = tid >> 4;
        int any = 0;
        for (int r = r0; r < 128; r += 16) {
            float4 v = *(const float4*)(mp + (size_t)r * TT + c);
            any |= (v.x != 0.f) | (v.y != 0.f) | (v.z != 0.f) | (v.w != 0.f);
        }
        any = __any(any) ? 1 : 0;
        if ((tid & 63) == 0) s_any[tid >> 6] = any;
        __syncthreads();
        if (tid == 0)
            flags[(bbm * 16 + tt) * 32 + st] = s_any[0] | s_any[1] | s_any[2] | s_any[3];
        return;
    }

    // ---- GEMM block ----
    int g = grp * 3 + rem;                           // [0,1536)
    int bx = g % 24, by = g / 24;
    int m0 = by * 128, n0 = bx * 128;
    f32x4 acc[4][4];
    gemm128_main(Xb, Wt, m0, n0, DD, smem, acc);

    const int w = tid >> 6, lane = tid & 63;
    const int wr = w >> 1, wc = w & 1, quad = lane >> 4, l16 = lane & 15;
    const int which = n0 >> 10;                      // 0=q,1=k,2=v (uniform per block)
    const int bbk = m0 >> 11, tbase = m0 & 2047;
    const int nn0 = n0 & 1023;                       // 128-aligned -> covers 2 heads

    if (which < 2) {
        const float* bias = which == 0 ? bq : bk;
        bf16* dst = which == 0 ? qb : kb;
        const float scl = which == 0 ? QSCALE : 1.0f;
#pragma unroll
        for (int phase = 0; phase < 2; phase++) {
            __syncthreads();
            if (wc == phase) {
#pragma unroll
                for (int mi = 0; mi < 4; mi++)
#pragma unroll
                    for (int ni = 0; ni < 4; ni++) {
                        int d = ni * 16 + l16;
                        float bb_ = bias[nn0 + phase * 64 + d];
#pragma unroll
                        for (int r = 0; r < 4; r++) {
                            int t_l = wr * 64 + mi * 16 + quad * 4 + r;
                            smem[t_l * 72 + d] = (bf16)((acc[mi][ni][r] + bb_) * scl);
                        }
                    }
            }
            __syncthreads();
            int hh = (nn0 + phase * 64) >> 6;
            bf16* dp = dst + (((size_t)bbk * NH + hh) * TT + tbase) * HD;
#pragma unroll
            for (int i = 0; i < 4; i++) {
                int idx = i * 256 + tid;             // 1024 16B-chunks (128 rows x 8)
                int rr = idx >> 3, cc = (idx & 7) * 8;
                *(bf16x8*)(dp + (size_t)rr * HD + cc) = *(const bf16x8*)(smem + rr * 72 + cc);
            }
        }
    } else {
        // V: transpose through LDS -> coalesced 16B stores into vt [B,H,64,T], t pi-permuted
#pragma unroll
        for (int phase = 0; phase < 2; phase++) {
            __syncthreads();
            if (wc == phase) {
#pragma unroll
                for (int mi = 0; mi < 4; mi++)
#pragma unroll
                    for (int ni = 0; ni < 4; ni++) {
                        int nn_l = ni * 16 + l16;
                        float bb_ = bv[nn0 + phase * 64 + nn_l];
#pragma unroll
                        for (int r = 0; r < 4; r++)
                            // pi: t_l = wr*64 + mi*16 + quad*4 + r  ->  wr*64 + quad*16 + mi*4 + r
                            smem[nn_l * 132 + wr * 64 + quad * 16 + mi * 4 + r] = (bf16)(acc[mi][ni][r] + bb_);
                    }
            }
            __syncthreads();
            int hh = (nn0 + phase * 64) >> 6;
#pragma unroll
            for (int i = 0; i < 4; i++) {
                int idx = i * 256 + tid;             // 1024 16B-chunks (64 rows x 16)
                int rr = idx >> 4, cc = (idx & 15) * 8;
                bf16x8 vv = *(const bf16x8*)(smem + rr * 132 + cc);
                *(bf16x8*)(vt + (((size_t)bbk * NH + hh) * HD + rr) * TT + tbase + cc) = vv;
            }
        }
    }
}

// ---------------- flash attention v4: dbuf K/V staging, hoisted Q frags, b128 V ----------------
__global__ __launch_bounds__(256, 4) void k_attn(const bf16* __restrict__ qb, const bf16* __restrict__ kb,
                                                 const bf16* __restrict__ vt, const float* __restrict__ mask,
                                                 const int* __restrict__ flags, bf16* __restrict__ ob) {
    __shared__ bf16 SB[4][4096];   // 32 KB: buf0 = SB[0](K),SB[1](V); buf1 = SB[2](K),SB[3](V)
    __shared__ int s_anyflag;      // Q is staged through SB[2..3] then lives in registers

    const int tq0 = blockIdx.x * 128;
    const int h = blockIdx.y, bb = blockIdx.z;
    const int tid = threadIdx.x, w = tid >> 6, lane = tid & 63;
    const int quad = lane >> 4, l16 = lane & 15;

    const bf16* Qg = qb + (((size_t)bb * NH + h) * TT + tq0) * HD;
    const bf16* Kg = kb + ((size_t)bb * NH + h) * TT * HD;
    const bf16* Vg = vt + ((size_t)bb * NH + h) * HD * TT;

    // loop-invariant staging constants (2 chunks each for K and V per thread)
    int cidx[2], koff[2], voff[2];
#pragma unroll
    for (int j = 0; j < 2; j++) {
        int idx = (w * 2 + j) * 64 + lane;
        int row = idx >> 3, m = idx & 7;
        cidx[j] = idx * 8;
        koff[j] = row * HD + ((m ^ (row & 7)) * 8);
        voff[j] = row * TT + ((m ^ (row & 7)) * 8);
    }

    // stage Q into SB[2..3] (swizzled), prefetch K/V tile 0 into buf0
#pragma unroll
    for (int j = 0; j < 4; j++) {
        int idx = (w * 4 + j) * 64 + lane;
        int row = idx >> 3, m = idx & 7;
        gload_lds16(Qg + row * HD + (m ^ (row & 7)) * 8, &SB[2][0] + idx * 8);
    }
#pragma unroll
    for (int j = 0; j < 2; j++) {
        gload_lds16(Kg + koff[j], SB[0] + cidx[j]);
        gload_lds16(Vg + voff[j], SB[1] + cidx[j]);
    }

    const int fbase = (bb * 16 + blockIdx.x) * 32;
    {
        int f0 = (tid < 32) ? flags[fbase + tid] : 0;
        if (tid < 64) { int a = __any(f0 != 0) ? 1 : 0; if (tid == 0) s_anyflag = a; }
    }

    bf16x8 ones;
#pragma unroll
    for (int i = 0; i < 8; i++) ones[i] = (bf16)1.0f;

    f32x4 oa[2][4];
    f32x4 lacc[2];
    f32x4 zero = {0.f, 0.f, 0.f, 0.f};
#pragma unroll
    for (int qi = 0; qi < 2; qi++) {
        lacc[qi] = zero;
#pragma unroll
        for (int ni = 0; ni < 4; ni++) oa[qi][ni] = zero;
    }

    __syncthreads();                    // drains Q + tile0; publishes s_anyflag
    const int anyflag = s_anyflag;

    // hoist Q fragments (loop-invariant across s): aq[kd][qi]
    bf16x8 aq[2][2];
#pragma unroll
    for (int kd = 0; kd < 2; kd++) {
        const int csw = ((kd * 4 + quad) ^ (l16 & 7)) * 8;
#pragma unroll
        for (int qi = 0; qi < 2; qi++)
            aq[kd][qi] = *(const bf16x8*)(&SB[2][0] + (w * 32 + qi * 16 + l16) * 64 + csw);
    }

#define ATTN_COMPUTE(Ks, Vs, S0)                                                              \
    {                                                                                         \
        f32x4 st[4][2];                                                                       \
        _Pragma("unroll") for (int si = 0; si < 4; si++)                                      \
            _Pragma("unroll") for (int qi = 0; qi < 2; qi++) st[si][qi] = zero;               \
        _Pragma("unroll") for (int kd = 0; kd < 2; kd++) {                                    \
            const int csw = ((kd * 4 + quad) ^ (l16 & 7)) * 8;                                \
            bf16x8 kf[4];                                                                     \
            _Pragma("unroll") for (int si = 0; si < 4; si++)                                  \
                kf[si] = *(const bf16x8*)((Ks) + (si * 16 + l16) * 64 + csw);                 \
            _Pragma("unroll") for (int si = 0; si < 4; si++)                                  \
                _Pragma("unroll") for (int qi = 0; qi < 2; qi++)                              \
                    st[si][qi] = __builtin_amdgcn_mfma_f32_16x16x32_bf16(kf[si], aq[kd][qi],  \
                                                                        st[si][qi], 0, 0, 0);\
        }                                                                                     \
        if (anyflag && flags[fbase + ((S0) >> 6)]) {                                          \
            const float* mp = mask + ((size_t)bb * TT + tq0) * TT + (S0);                     \
            _Pragma("unroll") for (int si = 0; si < 4; si++)                                  \
                _Pragma("unroll") for (int qi = 0; qi < 2; qi++)                              \
                    _Pragma("unroll") for (int r = 0; r < 4; r++)                             \
                        st[si][qi][r] += mp[(size_t)(w * 32 + qi * 16 + l16) * TT             \
                                            + si * 16 + quad * 4 + r] * LOG2E;                \
        }                                                                                     \
        bf16 ep[4][2][4];                                                                     \
        _Pragma("unroll") for (int si = 0; si < 4; si++)                                      \
            _Pragma("unroll") for (int qi = 0; qi < 2; qi++)                                  \
                _Pragma("unroll") for (int r = 0; r < 4; r++)                                 \
                    ep[si][qi][r] = (bf16)exp2f(st[si][qi][r]);                               \
        _Pragma("unroll") for (int kk = 0; kk < 2; kk++) {                                    \
            bf16x8 ap[2];                                                                     \
            _Pragma("unroll") for (int qi = 0; qi < 2; qi++)                                  \
                _Pragma("unroll") for (int j = 0; j < 8; j++)                                 \
                    ap[qi][j] = ep[2 * kk + (j >> 2)][qi][j & 3];                             \
            bf16x8 bv8[4];                                                                    \
            _Pragma("unroll") for (int ni = 0; ni < 4; ni++)                                  \
                bv8[ni] = *(const bf16x8*)((Vs) + (ni * 16 + l16) * 64                        \
                                           + ((quad * 2 + kk) ^ (l16 & 7)) * 8);              \
            _Pragma("unroll") for (int qi = 0; qi < 2; qi++)                                  \
                lacc[qi] = __builtin_amdgcn_mfma_f32_16x16x32_bf16(ap[qi], ones, lacc[qi],    \
                                                                   0, 0, 0);                  \
            _Pragma("unroll") for (int qi = 0; qi < 2; qi++)                                  \
                _Pragma("unroll") for (int ni = 0; ni < 4; ni++)                              \
                    oa[qi][ni] = __builtin_amdgcn_mfma_f32_16x16x32_bf16(ap[qi], bv8[ni],     \
                                                                         oa[qi][ni], 0, 0, 0);\
        }                                                                                     \
    }

    // iter 0 (tile 0 in buf0); no prefetch in flight yet
    ATTN_COMPUTE(SB[0], SB[1], 0)
    __syncthreads();                    // everyone done with Q-frag reads + tile0
    // prefetch tile 1 into buf1 (overwrites the staged-Q region; frags are in regs)
#pragma unroll
    for (int j = 0; j < 2; j++) {
        gload_lds16(Kg + 64 * HD + koff[j], SB[2] + cidx[j]);
        gload_lds16(Vg + 64 + voff[j], SB[3] + cidx[j]);
    }
    __syncthreads();                    // drains tile1 (one exposed latency per block)

    for (int i = 1; i < 32; i++) {
        const int cur = i & 1, nxt = cur ^ 1;
        if (i < 31) {
            const int sn = (i + 1) * 64;
#pragma unroll
            for (int j = 0; j < 2; j++) {
                gload_lds16(Kg + sn * HD + koff[j], SB[2 * nxt] + cidx[j]);
                gload_lds16(Vg + sn + voff[j], SB[2 * nxt + 1] + cidx[j]);
            }
        }
        ATTN_COMPUTE(SB[2 * cur], SB[2 * cur + 1], i * 64)
        __syncthreads();                // drains prefetch(i+1); guards buffer reuse
    }
#undef ATTN_COMPUTE

    // epilogue: normalize by row sums, write O as [B,T,D] bf16
#pragma unroll
    for (int qi = 0; qi < 2; qi++)
#pragma unroll
        for (int r = 0; r < 4; r++) {
            float inv = 1.f / lacc[qi][r];
            int trow = tq0 + w * 32 + qi * 16 + quad * 4 + r;
#pragma unroll
            for (int ni = 0; ni < 4; ni++) {
                float v = oa[qi][ni][r] * inv;
                ob[((size_t)bb * TT + trow) * DD + h * HD + ni * 16 + l16] = (bf16)v;
            }
        }
}

// ---------------- GEMM 2: O @ Wo + bo -> fp32 out ----------------
__global__ __launch_bounds__(256) void k_gemm_out(const bf16* __restrict__ Ob, const bf16* __restrict__ Wot,
                                                  const float* __restrict__ bo, float* __restrict__ out) {
    __shared__ bf16 smem[16384];
    int m0 = blockIdx.y * 128, n0 = blockIdx.x * 128;
    f32x4 acc[4][4];
    gemm128_main(Ob, Wot, m0, n0, DD, smem, acc);

    const int tid = threadIdx.x, w = tid >> 6, lane = tid & 63;
    const int wr = w >> 1, wc = w & 1, quad = lane >> 4, l16 = lane & 15;
#pragma unroll
    for (int mi = 0; mi < 4; mi++)
#pragma unroll
        for (int ni = 0; ni < 4; ni++) {
            int gn = n0 + wc * 64 + ni * 16 + l16;
            float bb_ = bo[gn];
#pragma unroll
            for (int r = 0; r < 4; r++) {
                int gm = m0 + wr * 64 + mi * 16 + quad * 4 + r;
                out[(size_t)gm * DD + gn] = acc[mi][ni][r] + bb_;
            }
        }
}

// ---------------- launch ----------------
extern "C" void kernel_launch(void* const* d_in, const int* in_sizes, int n_in,
                              void* d_out, int out_size, void* d_ws, size_t ws_size,
                              hipStream_t stream) {
    const float* hidden = (const float*)d_in[0];
    const float* mask   = (const float*)d_in[1];
    const float* Wq     = (const float*)d_in[2];
    const float* bq     = (const float*)d_in[3];
    const float* Wk     = (const float*)d_in[4];
    const float* bk     = (const float*)d_in[5];
    const float* Wv     = (const float*)d_in[6];
    const float* bv     = (const float*)d_in[7];
    const float* Wo     = (const float*)d_in[8];
    const float* bo     = (const float*)d_in[9];
    float* out = (float*)d_out;
    char* ws = (char*)d_ws;

    const size_t MB = 1024 * 1024;
    bf16* Xb   = (bf16*)(ws);               // 16 MB  [8192][1024]
    bf16* Wt   = (bf16*)(ws + 16 * MB);     //  8 MB  [4][1024][1024] n-major
    bf16* qb   = (bf16*)(ws + 24 * MB);     // 16 MB  [B][H][T][64] (pre-scaled by SCALING*LOG2E)
    bf16* kb   = (bf16*)(ws + 40 * MB);     // 16 MB  [B][H][T][64]
    bf16* vt   = (bf16*)(ws + 56 * MB);     // 16 MB  [B][H][64][T], t pi-permuted per 64-block
    bf16* ob   = (bf16*)(ws + 72 * MB);     // 16 MB  [8192][1024]
    int* flags = (int*)(ws + 88 * MB);      //  8 KB  [4][16][32]

    hipLaunchKernelGGL(k_prep, dim3(12288), dim3(256), 0, stream, hidden, Xb, Wq, Wk, Wv, Wo, Wt);
    hipLaunchKernelGGL(k_gemm_qkv, dim3(3584), dim3(256), 0, stream, Xb, Wt, bq, bk, bv, qb, kb, vt, mask, flags);
    hipLaunchKernelGGL(k_attn, dim3(16, 16, 4), dim3(256), 0, stream, qb, kb, vt, mask, flags, ob);
    hipLaunchKernelGGL(k_gemm_out, dim3(8, 64), dim3(256), 0, stream, ob, Wt + (size_t)3 * DD * DD, bo, out);
}